// Round 4
// baseline (387.995 us; speedup 1.0000x reference)
//
#include <hip/hip_runtime.h>
#include <math.h>

// SoftRasterizer: B=1, V=5023, F=10000, IMG=128.
// R4: tiled-rasterizer structure. k_bin builds per-16x16-tile face lists
// (ballot-compacted, face-ordered, deterministic). k_main: block (tile,seg)
// walks the tile list strided by S -> balanced work, no global cull scan.
// Eval arithmetic bit-identical to R3 (passed, absmax 3.9e-3) except
// dis/SIGMA -> dis*1e6f (Dp path only, no 1e6 amplification).

#define NFACE 10000
#define IMG   128
#define P_TOT (IMG*IMG)
#define FSTR  36               // floats per face record
#define NTILE 64               // 8x8 tiles of 16x16 px
#define CAP   10000            // per-tile list capacity

__device__ __forceinline__ float segd(float px, float py, float ax, float ay,
                                      float bx, float by, float il) {
    float dx = px - ax, dy = py - ay;
    float ex = bx - ax, ey = by - ay;
    float t = (dx * ex + dy * ey) * il;
    t = fminf(fmaxf(t, 0.0f), 1.0f);
    float rx = dx - t * ex, ry = dy - t * ey;
    return rx * rx + ry * ry;
}

__global__ __launch_bounds__(256) void k_pre(const float* __restrict__ v,
                                             const int* __restrict__ fc,
                                             const float* __restrict__ at,
                                             float* __restrict__ fb) {
    int f = blockIdx.x * 256 + threadIdx.x;
    if (f >= NFACE) return;
    int i0 = fc[3 * f], i1 = fc[3 * f + 1], i2 = fc[3 * f + 2];
    float x0 = -v[3 * i0], y0 = v[3 * i0 + 1], z0 = v[3 * i0 + 2];
    float x1 = -v[3 * i1], y1 = v[3 * i1 + 1], z1 = v[3 * i1 + 2];
    float x2 = -v[3 * i2], y2 = v[3 * i2 + 1], z2 = v[3 * i2 + 2];

    float det = (y1 - y2) * (x0 - x2) + (x2 - x1) * (y0 - y2);
    if (fabsf(det) < 1e-10f) det = (det < 0.0f) ? -1e-10f : 1e-10f;
    float a0 = y1 - y2, b0 = x2 - x1, a1 = y2 - y0, b1 = x0 - x2, detp = det;
    if (det < 0.0f) { detp = -det; a0 = -a0; b0 = -b0; a1 = -a1; b1 = -b1; }

    float a2 = a0 + a1, b2 = b0 + b1;
    float g0 = sqrtf(a0 * a0 + b0 * b0);
    float g1 = sqrtf(a1 * a1 + b1 * b1);
    float g2 = sqrtf(a2 * a2 + b2 * b2);
    const float MARG = 3e-5f, AG = 1e-9f;
    float m0 = -(MARG * g0 + AG), m1 = -(MARG * g1 + AG), m2 = -(MARG * g2 + AG);

    float e01x = x1 - x0, e01y = y1 - y0;
    float e12x = x2 - x1, e12y = y2 - y1;
    float e20x = x0 - x2, e20y = y0 - y2;
    float il01 = 1.0f / fmaxf(e01x * e01x + e01y * e01y, 1e-12f);
    float il12 = 1.0f / fmaxf(e12x * e12x + e12y * e12y, 1e-12f);
    float il20 = 1.0f / fmaxf(e20x * e20x + e20y * e20y, 1e-12f);

    const float BM = 2e-5f;
    float bxmin = fminf(fminf(x0, x1), x2) - BM, bxmax = fmaxf(fmaxf(x0, x1), x2) + BM;
    float bymin = fminf(fminf(y0, y1), y2) - BM, bymax = fmaxf(fmaxf(y0, y1), y2) + BM;

    int mult = (((y2 - y0) * (x1 - x0)) < ((y1 - y0) * (x2 - x0)))
             + (((y0 - y2) * (x1 - x2)) < ((y1 - y2) * (x0 - x2)));

    float* F = fb + (size_t)f * FSTR;
    F[0] = x0; F[1] = y0; F[2] = x1; F[3] = y1; F[4] = x2; F[5] = y2;
    F[6] = z0; F[7] = z1; F[8] = z2;
    F[9] = a0; F[10] = b0; F[11] = a1; F[12] = b1; F[13] = detp;
    F[14] = m0; F[15] = m1; F[16] = m2;
    F[17] = il01; F[18] = il12; F[19] = il20;
    F[20] = bxmin; F[21] = bxmax; F[22] = bymin; F[23] = bymax;
    F[24] = (float)mult;
#pragma unroll
    for (int k = 0; k < 9; k++) F[25 + k] = at[(size_t)f * 9 + k];
    F[34] = 0.0f; F[35] = 0.0f;
}

// one wave per tile; ballot-compacted ordered list (deterministic)
__global__ __launch_bounds__(64) void k_bin(const float* __restrict__ fb,
                                            int* __restrict__ lists,
                                            int* __restrict__ counts) {
    int t = blockIdx.x;
    int lane = threadIdx.x;
    int tx = t & 7, ty = t >> 3;
    // tile pixel bounds in NDC
    float x_lo = (float)(2 * (tx * 16) + 1 - IMG) / (float)IMG;
    float x_hi = (float)(2 * (tx * 16 + 15) + 1 - IMG) / (float)IMG;
    float y_hi = (float)(127 - 2 * (ty * 16)) / (float)IMG;
    float y_lo = (float)(127 - 2 * (ty * 16 + 15)) / (float)IMG;

    int cnt = 0;
    for (int base = 0; base < NFACE; base += 64) {
        int f = base + lane;
        bool ov = false;
        if (f < NFACE) {
            const float* F = fb + (size_t)f * FSTR;
            float bxmin = F[20], bxmax = F[21], bymin = F[22], bymax = F[23];
            ov = (bxmin <= x_hi) & (bxmax >= x_lo) & (bymin <= y_hi) & (bymax >= y_lo);
        }
        unsigned long long mask = __ballot(ov);
        if (ov) {
            int pos = __popcll(mask & ((1ull << lane) - 1ull));
            lists[(size_t)t * CAP + cnt + pos] = f;
        }
        cnt += __popcll(mask);
    }
    if (lane == 0) counts[t] = cnt;
}

__global__ __launch_bounds__(256) void k_main(const float* __restrict__ fb,
                                              const int* __restrict__ lists,
                                              const int* __restrict__ counts,
                                              float* __restrict__ part) {
    int tid = threadIdx.x;
    int t = blockIdx.x;
    int seg = blockIdx.y, S = gridDim.y;
    int tx = t & 7, ty = t >> 3;
    int col = tx * 16 + (tid & 15);
    int row = ty * 16 + (tid >> 4);
    float px = (float)(2 * col + 1 - IMG) / (float)IMG;
    float py = (float)(2 * (IMG - 1 - row) + 1 - IMG) / (float)IMG;

    int len = counts[t];
    const int* lst = lists + (size_t)t * CAP;

    float m = -__builtin_inff();
    float s = 0.0f, ca = 0.0f, cb = 0.0f, cc = 0.0f, pr = 1.0f;

    for (int i = seg; i < len; i += S) {
        int fj = __builtin_amdgcn_readfirstlane(lst[i]);
        const float* F = fb + (size_t)fj * FSTR;

        float bxmin = F[20], bxmax = F[21], bymin = F[22], bymax = F[23];
        bool inbox = (px >= bxmin) & (px <= bxmax) & (py >= bymin) & (py <= bymax);
        if (!__any(inbox)) continue;

        float x2 = F[4], y2 = F[5];
        float dx2 = px - x2, dy2 = py - y2;
        float a0 = F[9], b0 = F[10], a1 = F[11], b1 = F[12], detp = F[13];
        float num0 = a0 * dx2 + b0 * dy2;
        float num1 = a1 * dx2 + b1 * dy2;
        float num2 = detp - num0 - num1;
        bool maybe = inbox & (num0 >= F[14]) & (num1 >= F[15]) & (num2 >= F[16]);
        if (!__any(maybe)) continue;

        float x0 = F[0], y0 = F[1], x1 = F[2], y1 = F[3];
        float d01 = segd(px, py, x0, y0, x1, y1, F[17]);
        float d12 = segd(px, py, x1, y1, x2, y2, F[18]);
        float d20 = segd(px, py, x2, y2, x0, y0, F[19]);
        float dis = fminf(fminf(d01, d12), d20);

        float w0 = num0 / detp;       // bitwise == ref num/det
        float w1 = num1 / detp;
        float w2 = 1.0f - w0 - w1;
        bool inside = (w0 >= 0.0f) & (w1 >= 0.0f) & (w2 >= 0.0f);
        bool contrib = maybe & (inside | (dis < 1e-10f));
        if (!__any(contrib)) continue;

        float q = dis * 1e6f;         // / SIGMA (Dp path only)
        float xs_ = inside ? q : -q;
        float tt = expf(-fabsf(xs_));
        float Dp = (xs_ >= 0.0f ? 1.0f : tt) / (1.0f + tt);
        Dp = contrib ? Dp : 0.0f;
        float omd = 1.0f - Dp;
        pr *= contrib ? (omd * omd) : 1.0f;   // both winding copies

        float multf = F[24];
        bool doz = contrib & (multf > 0.0f);
        if (__any(doz)) {
            float c0 = fminf(fmaxf(w0, 0.0f), 1.0f);
            float c1 = fminf(fmaxf(w1, 0.0f), 1.0f);
            float c2 = fminf(fmaxf(w2, 0.0f), 1.0f);
            float csum = fmaxf(c0 + c1 + c2, 1e-5f);
            c0 = c0 / csum; c1 = c1 / csum; c2 = c2 / csum;
            float zpi = c0 / F[6] + c1 / F[7] + c2 / F[8];
            if (fabsf(zpi) < 1e-12f) zpi = 1e-12f;
            float zp = 1.0f / zpi;
            if (doz & (zp >= 1.0f) & (zp <= 100.0f)) {
                float zpn = (100.0f - zp) / 99.0f;
                if (zpn > m) {
                    float scl = expf((m - zpn) * 1e6f);
                    s *= scl; ca *= scl; cb *= scl; cc *= scl;
                    m = zpn;
                }
                float arg = (zpn - m) * 1e6f;
                if (arg > -110.0f) {
                    float e = expf(arg) * Dp * multf;
                    float col0 = c0 * F[25] + c1 * F[28] + c2 * F[31];
                    float col1 = c0 * F[26] + c1 * F[29] + c2 * F[32];
                    float col2 = c0 * F[27] + c1 * F[30] + c2 * F[33];
                    s += e; ca += e * col0; cb += e * col1; cc += e * col2;
                }
            }
        }
    }

    size_t pb = ((size_t)(t * S + seg) * 6) * 256;
    part[pb + 0 * 256 + tid] = m;
    part[pb + 1 * 256 + tid] = s;
    part[pb + 2 * 256 + tid] = ca;
    part[pb + 3 * 256 + tid] = cb;
    part[pb + 4 * 256 + tid] = cc;
    part[pb + 5 * 256 + tid] = pr;
}

__global__ __launch_bounds__(256) void k_reduce(const float* __restrict__ part,
                                                float* __restrict__ out,
                                                int S) {
    int t = blockIdx.x;
    int q = threadIdx.x;
    int tx = t & 7, ty = t >> 3;
    int col = tx * 16 + (q & 15);
    int row = ty * 16 + (q >> 4);
    int p = row * IMG + col;

    float m = 0.001f;   // BG_EPS
    for (int sgi = 0; sgi < S; sgi++)
        m = fmaxf(m, part[((size_t)(t * S + sgi) * 6 + 0) * 256 + q]);
    float sum = expf((0.001f - m) * 1e6f);   // background term (s0=1)
    float a = 0.0f, b = 0.0f, c = 0.0f, pr = 1.0f;
    for (int sgi = 0; sgi < S; sgi++) {
        const float* r = part + ((size_t)(t * S + sgi) * 6) * 256;
        float w = expf((r[0 * 256 + q] - m) * 1e6f);   // exp(-inf)=0 for empty
        sum += r[1 * 256 + q] * w;
        a += r[2 * 256 + q] * w;
        b += r[3 * 256 + q] * w;
        c += r[4 * 256 + q] * w;
        pr *= r[5 * 256 + q];
    }
    out[0 * P_TOT + p] = a / sum;
    out[1 * P_TOT + p] = b / sum;
    out[2 * P_TOT + p] = c / sum;
    out[3 * P_TOT + p] = 1.0f - pr;
}

extern "C" void kernel_launch(void* const* d_in, const int* in_sizes, int n_in,
                              void* d_out, int out_size, void* d_ws, size_t ws_size,
                              hipStream_t stream) {
    const float* verts = (const float*)d_in[0];
    const int*   faces = (const int*)d_in[1];
    const float* attrs = (const float*)d_in[2];
    float* out = (float*)d_out;
    float* ws  = (float*)d_ws;

    float* fb     = ws;                                        // 1.44 MB
    int*   lists  = (int*)(ws + (size_t)NFACE * FSTR);         // 2.56 MB
    int*   counts = lists + (size_t)NTILE * CAP;               // 64
    float* part   = (float*)(counts + 64);

    // choose S from remaining workspace (deterministic, host-side)
    size_t used_f  = (size_t)NFACE * FSTR + (size_t)NTILE * CAP + 64;
    long   rem_f   = (long)(ws_size / 4) - (long)used_f;
    int S = (int)(rem_f / (NTILE * 6 * 256));
    if (S > 40) S = 40;
    if (S < 4)  S = 4;

    k_pre<<<(NFACE + 255) / 256, 256, 0, stream>>>(verts, faces, attrs, fb);
    k_bin<<<NTILE, 64, 0, stream>>>(fb, lists, counts);
    k_main<<<dim3(NTILE, S), 256, 0, stream>>>(fb, lists, counts, part);
    k_reduce<<<NTILE, 256, 0, stream>>>(part, out, S);
}

// Round 5
// 246.257 us; speedup vs baseline: 1.5756x; 1.5756x over previous
//
#include <hip/hip_runtime.h>
#include <math.h>

// SoftRasterizer: B=1, V=5023, F=10000, IMG=128.
// R5: (1) work-proportional block assignment across tiles (k_map builds
// S_t ~ len_t, block->(tile,seg) map) to kill the heavy-tile tail
// (VALUBusy was 50% = half-idle makespan). (2) eval instruction diet:
// per-face 1/detp, 1/z precomputed exactly; csum/zpi/sigmoid denom via
// v_rcp+NR; expf -> __expf. zpn=(100-zp)/99 kept IEEE. Perturbation vs
// ref <= ~3ulp on zp -> softmax arg err ~0.03 -> well under threshold.

#define NFACE 10000
#define IMG   128
#define P_TOT (IMG*IMG)
#define FSTR  36               // floats per face record
#define NTILE 64               // 8x8 tiles of 16x16 px
#define CAP   10000            // per-tile list capacity
#define BMAX  2560             // max k_main blocks

__device__ __forceinline__ float rcp_nr(float x) {
    float r = __builtin_amdgcn_rcpf(x);
    r = r * __builtin_fmaf(-x, r, 2.0f);   // one Newton step -> ~1 ulp
    return r;
}

__device__ __forceinline__ float segd(float px, float py, float ax, float ay,
                                      float bx, float by, float il) {
    float dx = px - ax, dy = py - ay;
    float ex = bx - ax, ey = by - ay;
    float t = (dx * ex + dy * ey) * il;
    t = fminf(fmaxf(t, 0.0f), 1.0f);
    float rx = dx - t * ex, ry = dy - t * ey;
    return rx * rx + ry * ry;
}

// record: 0..5 xy012 | 6..8 1/z | 9..13 a0 b0 a1 b1 detp | 14..16 margins
// 17..19 il | 20..23 bbox | 24 mult | 25..33 tex | 34 rdetp | 35 pad
__global__ __launch_bounds__(256) void k_pre(const float* __restrict__ v,
                                             const int* __restrict__ fc,
                                             const float* __restrict__ at,
                                             float* __restrict__ fb) {
    int f = blockIdx.x * 256 + threadIdx.x;
    if (f >= NFACE) return;
    int i0 = fc[3 * f], i1 = fc[3 * f + 1], i2 = fc[3 * f + 2];
    float x0 = -v[3 * i0], y0 = v[3 * i0 + 1], z0 = v[3 * i0 + 2];
    float x1 = -v[3 * i1], y1 = v[3 * i1 + 1], z1 = v[3 * i1 + 2];
    float x2 = -v[3 * i2], y2 = v[3 * i2 + 1], z2 = v[3 * i2 + 2];

    float det = (y1 - y2) * (x0 - x2) + (x2 - x1) * (y0 - y2);
    if (fabsf(det) < 1e-10f) det = (det < 0.0f) ? -1e-10f : 1e-10f;
    float a0 = y1 - y2, b0 = x2 - x1, a1 = y2 - y0, b1 = x0 - x2, detp = det;
    if (det < 0.0f) { detp = -det; a0 = -a0; b0 = -b0; a1 = -a1; b1 = -b1; }

    float a2 = a0 + a1, b2 = b0 + b1;
    float g0 = sqrtf(a0 * a0 + b0 * b0);
    float g1 = sqrtf(a1 * a1 + b1 * b1);
    float g2 = sqrtf(a2 * a2 + b2 * b2);
    const float MARG = 3e-5f, AG = 1e-9f;
    float m0 = -(MARG * g0 + AG), m1 = -(MARG * g1 + AG), m2 = -(MARG * g2 + AG);

    float e01x = x1 - x0, e01y = y1 - y0;
    float e12x = x2 - x1, e12y = y2 - y1;
    float e20x = x0 - x2, e20y = y0 - y2;
    float il01 = 1.0f / fmaxf(e01x * e01x + e01y * e01y, 1e-12f);
    float il12 = 1.0f / fmaxf(e12x * e12x + e12y * e12y, 1e-12f);
    float il20 = 1.0f / fmaxf(e20x * e20x + e20y * e20y, 1e-12f);

    const float BM = 2e-5f;
    float bxmin = fminf(fminf(x0, x1), x2) - BM, bxmax = fmaxf(fmaxf(x0, x1), x2) + BM;
    float bymin = fminf(fminf(y0, y1), y2) - BM, bymax = fmaxf(fmaxf(y0, y1), y2) + BM;

    int mult = (((y2 - y0) * (x1 - x0)) < ((y1 - y0) * (x2 - x0)))
             + (((y0 - y2) * (x1 - x2)) < ((y1 - y2) * (x0 - x2)));

    float* F = fb + (size_t)f * FSTR;
    F[0] = x0; F[1] = y0; F[2] = x1; F[3] = y1; F[4] = x2; F[5] = y2;
    F[6] = 1.0f / z0; F[7] = 1.0f / z1; F[8] = 1.0f / z2;   // exact IEEE, once
    F[9] = a0; F[10] = b0; F[11] = a1; F[12] = b1; F[13] = detp;
    F[14] = m0; F[15] = m1; F[16] = m2;
    F[17] = il01; F[18] = il12; F[19] = il20;
    F[20] = bxmin; F[21] = bxmax; F[22] = bymin; F[23] = bymax;
    F[24] = (float)mult;
#pragma unroll
    for (int k = 0; k < 9; k++) F[25 + k] = at[(size_t)f * 9 + k];
    F[34] = 1.0f / detp;                                    // exact IEEE, once
    F[35] = 0.0f;
}

// one wave per tile; ballot-compacted ordered list (deterministic)
__global__ __launch_bounds__(64) void k_bin(const float* __restrict__ fb,
                                            int* __restrict__ lists,
                                            int* __restrict__ counts) {
    int t = blockIdx.x;
    int lane = threadIdx.x;
    int tx = t & 7, ty = t >> 3;
    float x_lo = (float)(2 * (tx * 16) + 1 - IMG) / (float)IMG;
    float x_hi = (float)(2 * (tx * 16 + 15) + 1 - IMG) / (float)IMG;
    float y_hi = (float)(127 - 2 * (ty * 16)) / (float)IMG;
    float y_lo = (float)(127 - 2 * (ty * 16 + 15)) / (float)IMG;

    int cnt = 0;
    for (int base = 0; base < NFACE; base += 64) {
        int f = base + lane;
        bool ov = false;
        if (f < NFACE) {
            const float* F = fb + (size_t)f * FSTR;
            ov = (F[20] <= x_hi) & (F[21] >= x_lo) & (F[22] <= y_hi) & (F[23] >= y_lo);
        }
        unsigned long long mask = __ballot(ov);
        if (ov) {
            int pos = __popcll(mask & ((1ull << lane) - 1ull));
            lists[(size_t)t * CAP + cnt + pos] = f;
        }
        cnt += __popcll(mask);
    }
    if (lane == 0) counts[t] = cnt;
}

// one wave: S_t ~ len_t (sum <= B), prefix starts, block->(tile,seg) map
__global__ __launch_bounds__(64) void k_map(const int* __restrict__ counts,
                                            int* __restrict__ map,
                                            int* __restrict__ starts,
                                            int* __restrict__ segs,
                                            int B) {
    int lane = threadIdx.x;              // 0..63, one wave, 64 tiles
    int len = counts[lane];
    int tot = len;
    for (int o = 32; o > 0; o >>= 1) tot += __shfl_down(tot, o);
    tot = __shfl(tot, 0);
    int St = max(1, (int)(((long long)len * (long long)(B - NTILE)) /
                          (long long)max(tot, 1)));
    __shared__ int sS[64], sP[64];
    sS[lane] = St;
    __syncthreads();
    if (lane == 0) {
        int acc = 0;
        for (int t = 0; t < 64; ++t) { sP[t] = acc; acc += sS[t]; }
    }
    __syncthreads();
    for (int i = lane; i < B; i += 64) map[i] = -1;
    __syncthreads();
    int st = sP[lane];
    starts[lane] = st;
    segs[lane] = St;
    for (int s = 0; s < St; ++s) map[st + s] = (lane << 16) | s;
}

__global__ __launch_bounds__(256) void k_main(const float* __restrict__ fb,
                                              const int* __restrict__ lists,
                                              const int* __restrict__ counts,
                                              const int* __restrict__ map,
                                              const int* __restrict__ segs,
                                              float* __restrict__ part) {
    int bid = blockIdx.x;
    int mv = map[bid];
    if (mv < 0) return;
    int t = mv >> 16, seg = mv & 0xffff;
    int S = segs[t];
    int len = counts[t];

    int tid = threadIdx.x;
    int tx = t & 7, ty = t >> 3;
    int col = tx * 16 + (tid & 15);
    int row = ty * 16 + (tid >> 4);
    float px = (float)(2 * col + 1 - IMG) / (float)IMG;
    float py = (float)(2 * (IMG - 1 - row) + 1 - IMG) / (float)IMG;

    const int* lst = lists + (size_t)t * CAP;

    float m = -__builtin_inff();
    float s = 0.0f, ca = 0.0f, cb = 0.0f, cc = 0.0f, pr = 1.0f;

    for (int i = seg; i < len; i += S) {
        int fj = __builtin_amdgcn_readfirstlane(lst[i]);
        const float* F = fb + (size_t)fj * FSTR;

        bool inbox = (px >= F[20]) & (px <= F[21]) & (py >= F[22]) & (py <= F[23]);
        if (!__any(inbox)) continue;

        float x2 = F[4], y2 = F[5];
        float dx2 = px - x2, dy2 = py - y2;
        float num0 = F[9] * dx2 + F[10] * dy2;
        float num1 = F[11] * dx2 + F[12] * dy2;
        float detp = F[13];
        float num2 = detp - num0 - num1;
        bool maybe = inbox & (num0 >= F[14]) & (num1 >= F[15]) & (num2 >= F[16]);
        if (!__any(maybe)) continue;

        float x0 = F[0], y0 = F[1], x1 = F[2], y1 = F[3];
        float d01 = segd(px, py, x0, y0, x1, y1, F[17]);
        float d12 = segd(px, py, x1, y1, x2, y2, F[18]);
        float d20 = segd(px, py, x2, y2, x0, y0, F[19]);
        float dis = fminf(fminf(d01, d12), d20);

        float rdetp = F[34];
        float w0 = num0 * rdetp;            // ~1 ulp vs ref num/det
        float w1 = num1 * rdetp;
        float w2 = 1.0f - w0 - w1;
        bool inside = (w0 >= 0.0f) & (w1 >= 0.0f) & (w2 >= 0.0f);
        bool contrib = maybe & (inside | (dis < 1e-10f));
        if (!__any(contrib)) continue;

        float q = dis * 1e6f;
        float xs_ = inside ? q : -q;
        float tt = __expf(-fabsf(xs_));
        float Dp = (xs_ >= 0.0f ? 1.0f : tt) * rcp_nr(1.0f + tt);
        Dp = contrib ? Dp : 0.0f;
        float omd = 1.0f - Dp;
        pr *= contrib ? (omd * omd) : 1.0f;   // both winding copies

        float multf = F[24];
        bool doz = contrib & (multf > 0.0f);
        if (__any(doz)) {
            float c0 = fminf(fmaxf(w0, 0.0f), 1.0f);
            float c1 = fminf(fmaxf(w1, 0.0f), 1.0f);
            float c2 = fminf(fmaxf(w2, 0.0f), 1.0f);
            float csum = fmaxf(c0 + c1 + c2, 1e-5f);
            float rcs = rcp_nr(csum);
            c0 *= rcs; c1 *= rcs; c2 *= rcs;
            float zpi = c0 * F[6] + c1 * F[7] + c2 * F[8];
            if (fabsf(zpi) < 1e-12f) zpi = 1e-12f;
            float zp = rcp_nr(zpi);
            if (doz & (zp >= 1.0f) & (zp <= 100.0f)) {
                float zpn = (100.0f - zp) / 99.0f;   // keep IEEE: critical
                if (zpn > m) {
                    float scl = __expf((m - zpn) * 1e6f);
                    s *= scl; ca *= scl; cb *= scl; cc *= scl;
                    m = zpn;
                }
                float arg = (zpn - m) * 1e6f;
                if (arg > -110.0f) {
                    float e = __expf(arg) * Dp * multf;
                    float col0 = c0 * F[25] + c1 * F[28] + c2 * F[31];
                    float col1 = c0 * F[26] + c1 * F[29] + c2 * F[32];
                    float col2 = c0 * F[27] + c1 * F[30] + c2 * F[33];
                    s += e; ca += e * col0; cb += e * col1; cc += e * col2;
                }
            }
        }
    }

    size_t pb = (size_t)bid * 6 * 256;
    part[pb + 0 * 256 + tid] = m;
    part[pb + 1 * 256 + tid] = s;
    part[pb + 2 * 256 + tid] = ca;
    part[pb + 3 * 256 + tid] = cb;
    part[pb + 4 * 256 + tid] = cc;
    part[pb + 5 * 256 + tid] = pr;
}

__global__ __launch_bounds__(256) void k_reduce(const float* __restrict__ part,
                                                const int* __restrict__ starts,
                                                const int* __restrict__ segs,
                                                float* __restrict__ out) {
    int t = blockIdx.x;
    int q = threadIdx.x;
    int tx = t & 7, ty = t >> 3;
    int col = tx * 16 + (q & 15);
    int row = ty * 16 + (q >> 4);
    int p = row * IMG + col;
    int start = starts[t], S = segs[t];

    float m = 0.001f;   // BG_EPS
    for (int sgi = 0; sgi < S; sgi++)
        m = fmaxf(m, part[((size_t)(start + sgi) * 6 + 0) * 256 + q]);
    float sum = __expf((0.001f - m) * 1e6f);   // background term (s0=1)
    float a = 0.0f, b = 0.0f, c = 0.0f, pr = 1.0f;
    for (int sgi = 0; sgi < S; sgi++) {
        const float* r = part + ((size_t)(start + sgi) * 6) * 256;
        float w = __expf((r[0 * 256 + q] - m) * 1e6f);   // exp(-inf)=0 for empty
        sum += r[1 * 256 + q] * w;
        a += r[2 * 256 + q] * w;
        b += r[3 * 256 + q] * w;
        c += r[4 * 256 + q] * w;
        pr *= r[5 * 256 + q];
    }
    out[0 * P_TOT + p] = a / sum;
    out[1 * P_TOT + p] = b / sum;
    out[2 * P_TOT + p] = c / sum;
    out[3 * P_TOT + p] = 1.0f - pr;
}

extern "C" void kernel_launch(void* const* d_in, const int* in_sizes, int n_in,
                              void* d_out, int out_size, void* d_ws, size_t ws_size,
                              hipStream_t stream) {
    const float* verts = (const float*)d_in[0];
    const int*   faces = (const int*)d_in[1];
    const float* attrs = (const float*)d_in[2];
    float* out = (float*)d_out;
    float* ws  = (float*)d_ws;

    float* fb     = ws;                                        // 1.44 MB
    int*   lists  = (int*)(ws + (size_t)NFACE * FSTR);         // 2.56 MB
    int*   counts = lists + (size_t)NTILE * CAP;               // 64
    int*   map    = counts + NTILE;                            // BMAX
    int*   starts = map + BMAX;                                // 64
    int*   segsum = starts + NTILE;                            // 64
    float* part   = (float*)(segsum + NTILE);

    size_t used_f = (size_t)NFACE * FSTR + (size_t)NTILE * CAP + NTILE + BMAX + 2 * NTILE;
    long   rem_f  = (long)(ws_size / 4) - (long)used_f;
    int B = (int)(rem_f / (6 * 256));
    if (B > BMAX) B = BMAX;
    if (B < 256)  B = 256;

    k_pre<<<(NFACE + 255) / 256, 256, 0, stream>>>(verts, faces, attrs, fb);
    k_bin<<<NTILE, 64, 0, stream>>>(fb, lists, counts);
    k_map<<<1, 64, 0, stream>>>(counts, map, starts, segsum, B);
    k_main<<<B, 256, 0, stream>>>(fb, lists, counts, map, segsum, part);
    k_reduce<<<NTILE, 256, 0, stream>>>(part, starts, segsum, out);
}

// Round 6
// 203.484 us; speedup vs baseline: 1.9068x; 1.2102x over previous
//
#include <hip/hip_runtime.h>
#include <math.h>

// SoftRasterizer: B=1, V=5023, F=10000, IMG=128.
// R6: exactness-preserving skip logic on top of R5 (passed, 246us):
//  - Dp==1.0f bit-exact when min_k(num_k*rg_k) > 4.3e-3 (sigmoid saturates)
//    -> skip segdists+sigmoid; per-edge wave gating otherwise.
//  - zp/color chain skipped when zpn_ub <= m - 1.3e-4 (exp flushes to 0.0f
//    bit-exact, no max update possible).
//  - k_bin: 256 thr/block + LDS cross-wave scan. k_reduce: skip zero-weight
//    segment loads.

#define NFACE 10000
#define IMG   128
#define P_TOT (IMG*IMG)
#define FSTR  40               // floats per face record
#define NTILE 64               // 8x8 tiles of 16x16 px
#define CAP   10000            // per-tile list capacity
#define BMAX  2560             // max k_main blocks

__device__ __forceinline__ float rcp_nr(float x) {
    float r = __builtin_amdgcn_rcpf(x);
    r = r * __builtin_fmaf(-x, r, 2.0f);   // one Newton step -> ~1 ulp
    return r;
}

__device__ __forceinline__ float segd(float px, float py, float ax, float ay,
                                      float bx, float by, float il) {
    float dx = px - ax, dy = py - ay;
    float ex = bx - ax, ey = by - ay;
    float t = (dx * ex + dy * ey) * il;
    t = fminf(fmaxf(t, 0.0f), 1.0f);
    float rx = dx - t * ex, ry = dy - t * ey;
    return rx * rx + ry * ry;
}

// record: 0..5 xy012 | 6..8 1/z | 9..12 a0 b0 a1 b1 | 13 detp | 14..16 margins
// 17..19 il | 20..23 bbox | 24 mult | 25..33 tex | 34 rdetp | 35 zpn_ub
// 36..38 rg0..2 | 39 pad
__global__ __launch_bounds__(256) void k_pre(const float* __restrict__ v,
                                             const int* __restrict__ fc,
                                             const float* __restrict__ at,
                                             float* __restrict__ fb) {
    int f = blockIdx.x * 256 + threadIdx.x;
    if (f >= NFACE) return;
    int i0 = fc[3 * f], i1 = fc[3 * f + 1], i2 = fc[3 * f + 2];
    float x0 = -v[3 * i0], y0 = v[3 * i0 + 1], z0 = v[3 * i0 + 2];
    float x1 = -v[3 * i1], y1 = v[3 * i1 + 1], z1 = v[3 * i1 + 2];
    float x2 = -v[3 * i2], y2 = v[3 * i2 + 1], z2 = v[3 * i2 + 2];

    float det = (y1 - y2) * (x0 - x2) + (x2 - x1) * (y0 - y2);
    if (fabsf(det) < 1e-10f) det = (det < 0.0f) ? -1e-10f : 1e-10f;
    float a0 = y1 - y2, b0 = x2 - x1, a1 = y2 - y0, b1 = x0 - x2, detp = det;
    if (det < 0.0f) { detp = -det; a0 = -a0; b0 = -b0; a1 = -a1; b1 = -b1; }

    float a2 = a0 + a1, b2 = b0 + b1;
    float g0 = fmaxf(sqrtf(a0 * a0 + b0 * b0), 1e-12f);
    float g1 = fmaxf(sqrtf(a1 * a1 + b1 * b1), 1e-12f);
    float g2 = fmaxf(sqrtf(a2 * a2 + b2 * b2), 1e-12f);
    const float MARG = 3e-5f, AG = 1e-9f;
    float m0 = -(MARG * g0 + AG), m1 = -(MARG * g1 + AG), m2 = -(MARG * g2 + AG);

    float e01x = x1 - x0, e01y = y1 - y0;
    float e12x = x2 - x1, e12y = y2 - y1;
    float e20x = x0 - x2, e20y = y0 - y2;
    float il01 = 1.0f / fmaxf(e01x * e01x + e01y * e01y, 1e-12f);
    float il12 = 1.0f / fmaxf(e12x * e12x + e12y * e12y, 1e-12f);
    float il20 = 1.0f / fmaxf(e20x * e20x + e20y * e20y, 1e-12f);

    const float BM = 2e-5f;
    float bxmin = fminf(fminf(x0, x1), x2) - BM, bxmax = fmaxf(fmaxf(x0, x1), x2) + BM;
    float bymin = fminf(fminf(y0, y1), y2) - BM, bymax = fmaxf(fmaxf(y0, y1), y2) + BM;

    int mult = (((y2 - y0) * (x1 - x0)) < ((y1 - y0) * (x2 - x0)))
             + (((y0 - y2) * (x1 - x2)) < ((y1 - y2) * (x0 - x2)));

    float zmin = fminf(fminf(z0, z1), z2);
    float zpn_ub = (100.0f - zmin) / 99.0f + 2e-6f;   // safe upper bound on zpn

    float* F = fb + (size_t)f * FSTR;
    F[0] = x0; F[1] = y0; F[2] = x1; F[3] = y1; F[4] = x2; F[5] = y2;
    F[6] = 1.0f / z0; F[7] = 1.0f / z1; F[8] = 1.0f / z2;
    F[9] = a0; F[10] = b0; F[11] = a1; F[12] = b1; F[13] = detp;
    F[14] = m0; F[15] = m1; F[16] = m2;
    F[17] = il01; F[18] = il12; F[19] = il20;
    F[20] = bxmin; F[21] = bxmax; F[22] = bymin; F[23] = bymax;
    F[24] = (float)mult;
#pragma unroll
    for (int k = 0; k < 9; k++) F[25 + k] = at[(size_t)f * 9 + k];
    F[34] = 1.0f / detp;
    F[35] = zpn_ub;
    F[36] = 1.0f / g0; F[37] = 1.0f / g1; F[38] = 1.0f / g2;
    F[39] = 0.0f;
}

// 256 threads/block, one block per tile; deterministic ordered compaction
__global__ __launch_bounds__(256) void k_bin(const float* __restrict__ fb,
                                             int* __restrict__ lists,
                                             int* __restrict__ counts) {
    int t = blockIdx.x;
    int tid = threadIdx.x, wv = tid >> 6, lane = tid & 63;
    int tx = t & 7, ty = t >> 3;
    float x_lo = (float)(2 * (tx * 16) + 1 - IMG) / (float)IMG;
    float x_hi = (float)(2 * (tx * 16 + 15) + 1 - IMG) / (float)IMG;
    float y_hi = (float)(127 - 2 * (ty * 16)) / (float)IMG;
    float y_lo = (float)(127 - 2 * (ty * 16 + 15)) / (float)IMG;

    __shared__ int wc[4];
    int cnt = 0;
    for (int base = 0; base < NFACE; base += 256) {
        int f = base + tid;
        bool ov = false;
        if (f < NFACE) {
            const float* F = fb + (size_t)f * FSTR;
            ov = (F[20] <= x_hi) & (F[21] >= x_lo) & (F[22] <= y_hi) & (F[23] >= y_lo);
        }
        unsigned long long mask = __ballot(ov);
        if (lane == 0) wc[wv] = __popcll(mask);
        __syncthreads();
        int off = cnt;
        for (int w = 0; w < 4; ++w) {
            if (w < wv) off += wc[w];
        }
        if (ov) {
            int pos = __popcll(mask & ((1ull << lane) - 1ull));
            lists[(size_t)t * CAP + off + pos] = f;
        }
        cnt += wc[0] + wc[1] + wc[2] + wc[3];
        __syncthreads();
    }
    if (tid == 0) counts[t] = cnt;
}

// one wave: S_t ~ len_t (sum <= B), prefix starts, block->(tile,seg) map
__global__ __launch_bounds__(64) void k_map(const int* __restrict__ counts,
                                            int* __restrict__ map,
                                            int* __restrict__ starts,
                                            int* __restrict__ segs,
                                            int B) {
    int lane = threadIdx.x;              // 0..63, one wave, 64 tiles
    int len = counts[lane];
    int tot = len;
    for (int o = 32; o > 0; o >>= 1) tot += __shfl_down(tot, o);
    tot = __shfl(tot, 0);
    int St = max(1, (int)(((long long)len * (long long)(B - NTILE)) /
                          (long long)max(tot, 1)));
    __shared__ int sS[64], sP[64];
    sS[lane] = St;
    __syncthreads();
    if (lane == 0) {
        int acc = 0;
        for (int t = 0; t < 64; ++t) { sP[t] = acc; acc += sS[t]; }
    }
    __syncthreads();
    for (int i = lane; i < B; i += 64) map[i] = -1;
    __syncthreads();
    int st = sP[lane];
    starts[lane] = st;
    segs[lane] = St;
    for (int s = 0; s < St; ++s) map[st + s] = (lane << 16) | s;
}

__global__ __launch_bounds__(256) void k_main(const float* __restrict__ fb,
                                              const int* __restrict__ lists,
                                              const int* __restrict__ counts,
                                              const int* __restrict__ map,
                                              const int* __restrict__ segs,
                                              float* __restrict__ part) {
    int bid = blockIdx.x;
    int mv = map[bid];
    if (mv < 0) return;
    int t = mv >> 16, seg = mv & 0xffff;
    int S = segs[t];
    int len = counts[t];

    int tid = threadIdx.x;
    int tx = t & 7, ty = t >> 3;
    int col = tx * 16 + (tid & 15);
    int row = ty * 16 + (tid >> 4);
    float px = (float)(2 * col + 1 - IMG) / (float)IMG;
    float py = (float)(2 * (IMG - 1 - row) + 1 - IMG) / (float)IMG;

    const int* lst = lists + (size_t)t * CAP;

    float m = -__builtin_inff();
    float s = 0.0f, ca = 0.0f, cb = 0.0f, cc = 0.0f, pr = 1.0f;

    const float NEAR_T = 4.3e-3f;   // lb > this => sigmoid rounds to 1.0f exactly

    for (int i = seg; i < len; i += S) {
        int fj = __builtin_amdgcn_readfirstlane(lst[i]);
        const float* F = fb + (size_t)fj * FSTR;

        bool inbox = (px >= F[20]) & (px <= F[21]) & (py >= F[22]) & (py <= F[23]);
        if (!__any(inbox)) continue;

        float x2 = F[4], y2 = F[5];
        float dx2 = px - x2, dy2 = py - y2;
        float num0 = F[9] * dx2 + F[10] * dy2;
        float num1 = F[11] * dx2 + F[12] * dy2;
        float detp = F[13];
        float num2 = detp - num0 - num1;
        bool maybe = inbox & (num0 >= F[14]) & (num1 >= F[15]) & (num2 >= F[16]);
        if (!__any(maybe)) continue;

        // inside test on numerators (detp > 0, same sign as ref's w tests)
        bool inside = (num0 >= 0.0f) & (num1 >= 0.0f) & (num2 >= 0.0f);
        bool inside_l = inside & inbox;

        // lower bound on edge distance (NDC): min over edge-line distances
        float lin0 = num0 * F[36];
        float lin1 = num1 * F[37];
        float lin2 = num2 * F[38];
        float lbmin = fminf(fminf(lin0, lin1), lin2);

        bool outNear = maybe & (!inside);            // within margins, outside
        bool nearIn  = inside_l & (lbmin < NEAR_T);  // inside, near an edge
        bool anyNear = __any(nearIn | outNear);

        float dis = 1e9f;
        float Dp;
        if (anyNear) {
            bool needAll = __any(outNear);
            float x0 = F[0], y0 = F[1], x1 = F[2], y1 = F[3];
            float d01 = 1e9f, d12 = 1e9f, d20 = 1e9f;
            if (needAll | __any(inside_l & (lin2 < NEAR_T)))   // edge v0-v1 (num2 grad)
                d01 = segd(px, py, x0, y0, x1, y1, F[17]);
            if (needAll | __any(inside_l & (lin0 < NEAR_T)))   // edge v1-v2
                d12 = segd(px, py, x1, y1, x2, y2, F[18]);
            if (needAll | __any(inside_l & (lin1 < NEAR_T)))   // edge v2-v0
                d20 = segd(px, py, x2, y2, x0, y0, F[19]);
            dis = fminf(fminf(d01, d12), d20);

            float q = dis * 1e6f;
            float xs_ = inside ? q : -q;
            float tt = __expf(-fabsf(xs_));
            float Dpn = (xs_ >= 0.0f ? 1.0f : tt) * rcp_nr(1.0f + tt);
            bool nearl = nearIn | outNear;
            Dp = nearl ? Dpn : (inside_l ? 1.0f : 0.0f);
        } else {
            Dp = inside_l ? 1.0f : 0.0f;
        }

        bool contrib = inside_l | (outNear & (dis < 1e-10f));
        Dp = contrib ? Dp : 0.0f;
        float omd = 1.0f - Dp;
        pr *= contrib ? (omd * omd) : 1.0f;   // both winding copies

        float multf = F[24];
        float zub = F[35];
        // skip exact: zub <= m - 1.3e-4 => exp flushes to 0.0f and zpn < m
        bool doz = contrib & (multf > 0.0f);
        if (__any(doz & (zub > m - 1.3e-4f))) {
            float rdetp = F[34];
            float w0 = num0 * rdetp;
            float w1 = num1 * rdetp;
            float c0 = fminf(fmaxf(w0, 0.0f), 1.0f);
            float c1 = fminf(fmaxf(w1, 0.0f), 1.0f);
            float c2 = fminf(fmaxf(1.0f - w0 - w1, 0.0f), 1.0f);
            float csum = fmaxf(c0 + c1 + c2, 1e-5f);
            float rcs = rcp_nr(csum);
            c0 *= rcs; c1 *= rcs; c2 *= rcs;
            float zpi = c0 * F[6] + c1 * F[7] + c2 * F[8];
            if (fabsf(zpi) < 1e-12f) zpi = 1e-12f;
            float zp = rcp_nr(zpi);
            if (doz & (zp >= 1.0f) & (zp <= 100.0f)) {
                float zpn = (100.0f - zp) / 99.0f;   // keep IEEE: critical
                if (zpn > m) {
                    float scl = __expf((m - zpn) * 1e6f);
                    s *= scl; ca *= scl; cb *= scl; cc *= scl;
                    m = zpn;
                }
                float arg = (zpn - m) * 1e6f;
                if (arg > -110.0f) {
                    float e = __expf(arg) * Dp * multf;
                    float col0 = c0 * F[25] + c1 * F[28] + c2 * F[31];
                    float col1 = c0 * F[26] + c1 * F[29] + c2 * F[32];
                    float col2 = c0 * F[27] + c1 * F[30] + c2 * F[33];
                    s += e; ca += e * col0; cb += e * col1; cc += e * col2;
                }
            }
        }
    }

    size_t pb = (size_t)bid * 6 * 256;
    part[pb + 0 * 256 + tid] = m;
    part[pb + 1 * 256 + tid] = s;
    part[pb + 2 * 256 + tid] = ca;
    part[pb + 3 * 256 + tid] = cb;
    part[pb + 4 * 256 + tid] = cc;
    part[pb + 5 * 256 + tid] = pr;
}

__global__ __launch_bounds__(256) void k_reduce(const float* __restrict__ part,
                                                const int* __restrict__ starts,
                                                const int* __restrict__ segs,
                                                float* __restrict__ out) {
    int t = blockIdx.x;
    int q = threadIdx.x;
    int tx = t & 7, ty = t >> 3;
    int col = tx * 16 + (q & 15);
    int row = ty * 16 + (q >> 4);
    int p = row * IMG + col;
    int start = starts[t], S = segs[t];

    float m = 0.001f;   // BG_EPS
    for (int sgi = 0; sgi < S; sgi++)
        m = fmaxf(m, part[((size_t)(start + sgi) * 6 + 0) * 256 + q]);
    float sum = __expf((0.001f - m) * 1e6f);   // background term (s0=1)
    float a = 0.0f, b = 0.0f, c = 0.0f, pr = 1.0f;
    for (int sgi = 0; sgi < S; sgi++) {
        const float* r = part + ((size_t)(start + sgi) * 6) * 256;
        float w = __expf((r[0 * 256 + q] - m) * 1e6f);   // exp(-inf)=0 for empty
        pr *= r[5 * 256 + q];
        if (__any(w != 0.0f)) {
            sum += r[1 * 256 + q] * w;
            a += r[2 * 256 + q] * w;
            b += r[3 * 256 + q] * w;
            c += r[4 * 256 + q] * w;
        }
    }
    out[0 * P_TOT + p] = a / sum;
    out[1 * P_TOT + p] = b / sum;
    out[2 * P_TOT + p] = c / sum;
    out[3 * P_TOT + p] = 1.0f - pr;
}

extern "C" void kernel_launch(void* const* d_in, const int* in_sizes, int n_in,
                              void* d_out, int out_size, void* d_ws, size_t ws_size,
                              hipStream_t stream) {
    const float* verts = (const float*)d_in[0];
    const int*   faces = (const int*)d_in[1];
    const float* attrs = (const float*)d_in[2];
    float* out = (float*)d_out;
    float* ws  = (float*)d_ws;

    float* fb     = ws;                                        // 1.6 MB
    int*   lists  = (int*)(ws + (size_t)NFACE * FSTR);         // 2.56 MB
    int*   counts = lists + (size_t)NTILE * CAP;               // 64
    int*   map    = counts + NTILE;                            // BMAX
    int*   starts = map + BMAX;                                // 64
    int*   segsum = starts + NTILE;                            // 64
    float* part   = (float*)(segsum + NTILE);

    size_t used_f = (size_t)NFACE * FSTR + (size_t)NTILE * CAP + NTILE + BMAX + 2 * NTILE;
    long   rem_f  = (long)(ws_size / 4) - (long)used_f;
    int B = (int)(rem_f / (6 * 256));
    if (B > BMAX) B = BMAX;
    if (B < 256)  B = 256;

    k_pre<<<(NFACE + 255) / 256, 256, 0, stream>>>(verts, faces, attrs, fb);
    k_bin<<<NTILE, 256, 0, stream>>>(fb, lists, counts);
    k_map<<<1, 64, 0, stream>>>(counts, map, starts, segsum, B);
    k_main<<<B, 256, 0, stream>>>(fb, lists, counts, map, segsum, part);
    k_reduce<<<NTILE, 256, 0, stream>>>(part, starts, segsum, out);
}